// Round 8
// baseline (195.749 us; speedup 1.0000x reference)
//
#include <hip/hip_runtime.h>

#define NUM_BINS 9900
#define NB4      2475      // NUM_BINS / 4, exact
#define ROW_P    1024
#define BLOCK    512

typedef float f32x4 __attribute__((ext_vector_type(4)));

__global__ __launch_bounds__(BLOCK) void binned_spectra_kernel(
    const float* __restrict__ mz,
    const float* __restrict__ inten,
    float* __restrict__ out)
{
    // Histogram as f32x4 so zero/readout use ds_write_b128/ds_read_b128.
    __shared__ f32x4 hist4[NB4];             // 39600 B -> 4 blocks/CU, 32 waves/CU
    float* hist = (float*)hist4;

    const int row = blockIdx.x;
    const int tid = threadIdx.x;

    // --- zero LDS histogram (vectorized) ---
    const f32x4 z = {0.0f, 0.0f, 0.0f, 0.0f};
    for (int j = tid; j < NB4; j += BLOCK) hist4[j] = z;
    __syncthreads();

    // --- scatter 1024 peaks: 2 per thread via float2 loads ---
    const float2 m2 = ((const float2*)(mz    + (size_t)row * ROW_P))[tid];
    const float2 v2 = ((const float2*)(inten + (size_t)row * ROW_P))[tid];

    #pragma unroll
    for (int k = 0; k < 2; ++k) {
        const float m = k ? m2.y : m2.x;
        const float v = k ? v2.y : v2.x;
        if (m >= 10.0f && m < 1000.0f) {
            // Match XLA lowering: (m - 10.0f) * 10.0f in strict fp32
            // (div-by-0.1f algebraically simplified to mul by 10.0f),
            // truncating cast, clip to [0, NUM_BINS-1].
            const float u = (m - 10.0f) * 10.0f;
            int idx = (int)u;
            idx = idx < 0 ? 0 : (idx > NUM_BINS - 1 ? NUM_BINS - 1 : idx);
            atomicAdd(&hist[idx], __fsqrt_rn(v));
        }
    }
    __syncthreads();

    // --- stream histogram to HBM: f32x4 nontemporal stores ---
    // row base = row * 39600 B, 16B-aligned (39600 % 16 == 0).
    f32x4* outr4 = (f32x4*)(out + (size_t)row * NUM_BINS);
    for (int j = tid; j < NB4; j += BLOCK)
        __builtin_nontemporal_store(hist4[j], &outr4[j]);
}

extern "C" void kernel_launch(void* const* d_in, const int* in_sizes, int n_in,
                              void* d_out, int out_size, void* d_ws, size_t ws_size,
                              hipStream_t stream)
{
    const float* mz    = (const float*)d_in[0];
    const float* inten = (const float*)d_in[1];
    float* out = (float*)d_out;

    const int rows = in_sizes[0] / ROW_P;  // 4096
    binned_spectra_kernel<<<rows, BLOCK, 0, stream>>>(mz, inten, out);
}